// Round 1
// baseline (1533.905 us; speedup 1.0000x reference)
//
#include <hip/hip_runtime.h>
#include <hip/hip_bf16.h>

// Phase 1: scatter-add feat[src] into agg[dst] (agg aliases d_out), plus degree histogram.
// One wave (64 lanes) per edge; each lane handles 2 floats of the 128-wide row.
__global__ void scatter_edges(const float* __restrict__ feat,
                              const int* __restrict__ src,
                              const int* __restrict__ dst,
                              float* agg,
                              float* __restrict__ deg,
                              int nE) {
    const int lane  = threadIdx.x & 63;
    const int wave  = (blockIdx.x * blockDim.x + threadIdx.x) >> 6;
    const int nWaves = (gridDim.x * blockDim.x) >> 6;
    for (int e = wave; e < nE; e += nWaves) {
        const int s = src[e];
        const int d = dst[e];
        const float2 v = reinterpret_cast<const float2*>(feat)[s * 64 + lane];
        atomicAdd(&agg[d * 128 + lane * 2 + 0], v.x);
        atomicAdd(&agg[d * 128 + lane * 2 + 1], v.y);
        if (lane == 0) atomicAdd(&deg[d], 1.0f);
    }
}

// Phase 2: out[n,:] = (agg[n,:] @ W) * rsqrt(max(deg[n],1)) + bias, in place (agg == out).
// Block = 256 threads computes a 64-row x 128-col tile; thread tile 4x8.
// In-place safety: all global reads of a block's rows happen before the final
// __syncthreads(); stores only in the epilogue; blocks touch disjoint rows.
__global__ __launch_bounds__(256) void gemm_norm(const float* agg,
                                                 const float* __restrict__ weight,
                                                 const float* __restrict__ bias,
                                                 const float* __restrict__ deg,
                                                 float* out, int M) {
    __shared__ float As[64][68];    // [row][k-chunk], +4 pad keeps float4 alignment, breaks conflicts
    __shared__ float Wc[64][128];   // [k-chunk][col]
    const int t   = threadIdx.x;
    const int tx  = t & 15;   // col group: cols tx*8 .. tx*8+7
    const int ty  = t >> 4;   // row group: rows ty*4 .. ty*4+3
    const int row0 = blockIdx.x * 64;

    float acc[4][8];
#pragma unroll
    for (int i = 0; i < 4; ++i)
#pragma unroll
        for (int j = 0; j < 8; ++j) acc[i][j] = 0.0f;

    for (int c = 0; c < 2; ++c) {
        if (c) __syncthreads();
        // Stage A chunk: rows row0..row0+63, k in [c*64, c*64+64)
        {
            const int k4    = (t & 15) * 4;
            const int rbase = t >> 4;  // 0..15
#pragma unroll
            for (int p = 0; p < 4; ++p) {
                const int rr   = rbase + p * 16;
                const int grow = row0 + rr;
                float4 v = make_float4(0.f, 0.f, 0.f, 0.f);
                if (grow < M)
                    v = *reinterpret_cast<const float4*>(&agg[grow * 128 + c * 64 + k4]);
                *reinterpret_cast<float4*>(&As[rr][k4]) = v;
            }
        }
        // Stage W chunk: k rows [c*64, c*64+64), all 128 cols (64*128 floats, 8 float4/thread)
        {
#pragma unroll
            for (int p = 0; p < 8; ++p) {
                const int idx = (p * 256 + t) * 4;
                const int kk  = idx >> 7;
                const int j   = idx & 127;
                *reinterpret_cast<float4*>(&Wc[kk][j]) =
                    *reinterpret_cast<const float4*>(&weight[(c * 64 + kk) * 128 + j]);
            }
        }
        __syncthreads();

#pragma unroll 8
        for (int k = 0; k < 64; ++k) {
            float a[4];
#pragma unroll
            for (int i = 0; i < 4; ++i) a[i] = As[ty * 4 + i][k];
            const float4 b0 = *reinterpret_cast<const float4*>(&Wc[k][tx * 8 + 0]);
            const float4 b1 = *reinterpret_cast<const float4*>(&Wc[k][tx * 8 + 4]);
            const float b[8] = {b0.x, b0.y, b0.z, b0.w, b1.x, b1.y, b1.z, b1.w};
#pragma unroll
            for (int i = 0; i < 4; ++i)
#pragma unroll
                for (int j = 0; j < 8; ++j)
                    acc[i][j] = fmaf(a[i], b[j], acc[i][j]);
        }
    }

    // Epilogue: scale by norm, add bias, store.
    float bcol[8];
#pragma unroll
    for (int j = 0; j < 8; ++j) bcol[j] = bias[tx * 8 + j];
#pragma unroll
    for (int i = 0; i < 4; ++i) {
        const int grow = row0 + ty * 4 + i;
        if (grow < M) {
            const float nm = rsqrtf(fmaxf(deg[grow], 1.0f));
            float4 o0, o1;
            o0.x = fmaf(acc[i][0], nm, bcol[0]);
            o0.y = fmaf(acc[i][1], nm, bcol[1]);
            o0.z = fmaf(acc[i][2], nm, bcol[2]);
            o0.w = fmaf(acc[i][3], nm, bcol[3]);
            o1.x = fmaf(acc[i][4], nm, bcol[4]);
            o1.y = fmaf(acc[i][5], nm, bcol[5]);
            o1.z = fmaf(acc[i][6], nm, bcol[6]);
            o1.w = fmaf(acc[i][7], nm, bcol[7]);
            *reinterpret_cast<float4*>(&out[grow * 128 + tx * 8 + 0]) = o0;
            *reinterpret_cast<float4*>(&out[grow * 128 + tx * 8 + 4]) = o1;
        }
    }
}

extern "C" void kernel_launch(void* const* d_in, const int* in_sizes, int n_in,
                              void* d_out, int out_size, void* d_ws, size_t ws_size,
                              hipStream_t stream) {
    const float* feat   = (const float*)d_in[0];
    const int*   src    = (const int*)d_in[1];
    const int*   dst    = (const int*)d_in[2];
    const float* weight = (const float*)d_in[3];
    const float* bias   = (const float*)d_in[4];
    float* out = (float*)d_out;

    const int nE = in_sizes[1];
    const int M  = in_sizes[0] / 128;

    float* deg = (float*)d_ws;  // M floats (400 KB)

    // Zero the aggregation buffer (d_out doubles as agg) and degrees.
    hipMemsetAsync(d_out, 0, (size_t)out_size * sizeof(float), stream);
    hipMemsetAsync(deg, 0, (size_t)M * sizeof(float), stream);

    // Phase 1: edge scatter (8192 waves, grid-stride over 1.6M edges).
    scatter_edges<<<2048, 256, 0, stream>>>(feat, src, dst, out, deg, nE);

    // Phase 2: fused GEMM + degree-norm + bias, in place on d_out.
    const int blocks = (M + 63) / 64;
    gemm_norm<<<blocks, 256, 0, stream>>>(out, weight, bias, deg, out, M);
}

// Round 2
// 464.417 us; speedup vs baseline: 3.3029x; 3.3029x over previous
//
#include <hip/hip_runtime.h>
#include <hip/hip_bf16.h>

#define CHUNK 1024

// ---------- CSR build ----------
__global__ void hist_kernel(const int* __restrict__ dst, int* __restrict__ deg, int nE) {
    int e = blockIdx.x * blockDim.x + threadIdx.x;
    if (e < nE) atomicAdd(&deg[dst[e]], 1);
}

// Per-chunk exclusive scan (chunk = 1024 elements, 256 threads x 4 elems).
__global__ __launch_bounds__(256) void scan_chunks(const int* __restrict__ deg,
                                                   int* __restrict__ off,
                                                   int* __restrict__ partials, int N) {
    __shared__ int sums[256];
    const int b = blockIdx.x, t = threadIdx.x;
    const int base = b * CHUNK + t * 4;
    int v[4];
#pragma unroll
    for (int i = 0; i < 4; ++i) v[i] = (base + i < N) ? deg[base + i] : 0;
    const int s = v[0] + v[1] + v[2] + v[3];
    sums[t] = s;
    __syncthreads();
    for (int d = 1; d < 256; d <<= 1) {
        int x = (t >= d) ? sums[t - d] : 0;
        __syncthreads();
        sums[t] += x;
        __syncthreads();
    }
    const int excl = sums[t] - s;
    if (t == 255) partials[b] = sums[255];
    int run = excl;
#pragma unroll
    for (int i = 0; i < 4; ++i) {
        if (base + i < N) off[base + i] = run;
        run += v[i];
    }
}

__global__ void scan_partials(int* partials, int P) {
    if (threadIdx.x == 0 && blockIdx.x == 0) {
        int acc = 0;
        for (int i = 0; i < P; ++i) { int v = partials[i]; partials[i] = acc; acc += v; }
    }
}

__global__ void add_base(int* __restrict__ off, int* __restrict__ cur,
                         const int* __restrict__ partials, int N) {
    int i = blockIdx.x * blockDim.x + threadIdx.x;
    if (i < N) {
        int o = off[i] + partials[i >> 10];
        off[i] = o;
        cur[i] = o;
    }
}

__global__ void bucket_edges(const int* __restrict__ src, const int* __restrict__ dst,
                             int* __restrict__ cur, int* __restrict__ csr, int nE) {
    int e = blockIdx.x * blockDim.x + threadIdx.x;
    if (e < nE) {
        int d = dst[e];
        int pos = atomicAdd(&cur[d], 1);
        csr[pos] = src[e];
    }
}

// ---------- atomic-free aggregation: one wave per node ----------
__global__ __launch_bounds__(256) void aggregate(const float* __restrict__ feat,
                                                 const int* __restrict__ csr,
                                                 const int* __restrict__ off,
                                                 const int* __restrict__ deg,
                                                 float* __restrict__ out, int N) {
    const int node = (blockIdx.x * blockDim.x + threadIdx.x) >> 6;
    if (node >= N) return;
    const int lane = threadIdx.x & 63;
    const int start = off[node];
    const int end   = start + deg[node];
    const float2* feat2 = reinterpret_cast<const float2*>(feat);

    float ax = 0.0f, ay = 0.0f;
    int j = start;
    for (; j + 3 < end; j += 4) {
        const int s0 = csr[j + 0], s1 = csr[j + 1], s2 = csr[j + 2], s3 = csr[j + 3];
        const float2 v0 = feat2[(size_t)s0 * 64 + lane];
        const float2 v1 = feat2[(size_t)s1 * 64 + lane];
        const float2 v2 = feat2[(size_t)s2 * 64 + lane];
        const float2 v3 = feat2[(size_t)s3 * 64 + lane];
        ax += v0.x + v1.x + v2.x + v3.x;
        ay += v0.y + v1.y + v2.y + v3.y;
    }
    for (; j < end; ++j) {
        const int s = csr[j];
        const float2 v = feat2[(size_t)s * 64 + lane];
        ax += v.x;
        ay += v.y;
    }
    reinterpret_cast<float2*>(out)[(size_t)node * 64 + lane] = make_float2(ax, ay);
}

// ---------- fallback (ws too small): fp32 atomic scatter ----------
__global__ void scatter_edges_fb(const float* __restrict__ feat,
                                 const int* __restrict__ src,
                                 const int* __restrict__ dst,
                                 float* agg, int* __restrict__ deg, int nE) {
    const int lane = threadIdx.x & 63;
    const int wave = (blockIdx.x * blockDim.x + threadIdx.x) >> 6;
    const int nWaves = (gridDim.x * blockDim.x) >> 6;
    for (int e = wave; e < nE; e += nWaves) {
        const int s = src[e];
        const int d = dst[e];
        const float2 v = reinterpret_cast<const float2*>(feat)[s * 64 + lane];
        atomicAdd(&agg[d * 128 + lane * 2 + 0], v.x);
        atomicAdd(&agg[d * 128 + lane * 2 + 1], v.y);
        if (lane == 0) atomicAdd(&deg[d], 1);
    }
}

// ---------- fused GEMM + norm + bias (in place, agg == out) ----------
__global__ __launch_bounds__(256) void gemm_norm(const float* agg,
                                                 const float* __restrict__ weight,
                                                 const float* __restrict__ bias,
                                                 const int* __restrict__ deg,
                                                 float* out, int M) {
    __shared__ float As[64][68];
    __shared__ float Wc[64][128];
    const int t  = threadIdx.x;
    const int tx = t & 15;
    const int ty = t >> 4;
    const int row0 = blockIdx.x * 64;

    float acc[4][8];
#pragma unroll
    for (int i = 0; i < 4; ++i)
#pragma unroll
        for (int j = 0; j < 8; ++j) acc[i][j] = 0.0f;

    for (int c = 0; c < 2; ++c) {
        if (c) __syncthreads();
        {
            const int k4 = (t & 15) * 4;
            const int rbase = t >> 4;
#pragma unroll
            for (int p = 0; p < 4; ++p) {
                const int rr = rbase + p * 16;
                const int grow = row0 + rr;
                float4 v = make_float4(0.f, 0.f, 0.f, 0.f);
                if (grow < M)
                    v = *reinterpret_cast<const float4*>(&agg[grow * 128 + c * 64 + k4]);
                *reinterpret_cast<float4*>(&As[rr][k4]) = v;
            }
        }
        {
#pragma unroll
            for (int p = 0; p < 8; ++p) {
                const int idx = (p * 256 + t) * 4;
                const int kk = idx >> 7;
                const int j = idx & 127;
                *reinterpret_cast<float4*>(&Wc[kk][j]) =
                    *reinterpret_cast<const float4*>(&weight[(c * 64 + kk) * 128 + j]);
            }
        }
        __syncthreads();

#pragma unroll 8
        for (int k = 0; k < 64; ++k) {
            float a[4];
#pragma unroll
            for (int i = 0; i < 4; ++i) a[i] = As[ty * 4 + i][k];
            const float4 b0 = *reinterpret_cast<const float4*>(&Wc[k][tx * 8 + 0]);
            const float4 b1 = *reinterpret_cast<const float4*>(&Wc[k][tx * 8 + 4]);
            const float b[8] = {b0.x, b0.y, b0.z, b0.w, b1.x, b1.y, b1.z, b1.w};
#pragma unroll
            for (int i = 0; i < 4; ++i)
#pragma unroll
                for (int j = 0; j < 8; ++j)
                    acc[i][j] = fmaf(a[i], b[j], acc[i][j]);
        }
    }

    float bcol[8];
#pragma unroll
    for (int j = 0; j < 8; ++j) bcol[j] = bias[tx * 8 + j];
#pragma unroll
    for (int i = 0; i < 4; ++i) {
        const int grow = row0 + ty * 4 + i;
        if (grow < M) {
            const float nm = rsqrtf(fmaxf((float)deg[grow], 1.0f));
            float4 o0, o1;
            o0.x = fmaf(acc[i][0], nm, bcol[0]);
            o0.y = fmaf(acc[i][1], nm, bcol[1]);
            o0.z = fmaf(acc[i][2], nm, bcol[2]);
            o0.w = fmaf(acc[i][3], nm, bcol[3]);
            o1.x = fmaf(acc[i][4], nm, bcol[4]);
            o1.y = fmaf(acc[i][5], nm, bcol[5]);
            o1.z = fmaf(acc[i][6], nm, bcol[6]);
            o1.w = fmaf(acc[i][7], nm, bcol[7]);
            *reinterpret_cast<float4*>(&out[grow * 128 + tx * 8 + 0]) = o0;
            *reinterpret_cast<float4*>(&out[grow * 128 + tx * 8 + 4]) = o1;
        }
    }
}

extern "C" void kernel_launch(void* const* d_in, const int* in_sizes, int n_in,
                              void* d_out, int out_size, void* d_ws, size_t ws_size,
                              hipStream_t stream) {
    const float* feat   = (const float*)d_in[0];
    const int*   src    = (const int*)d_in[1];
    const int*   dst    = (const int*)d_in[2];
    const float* weight = (const float*)d_in[3];
    const float* bias   = (const float*)d_in[4];
    float* out = (float*)d_out;

    const int nE = in_sizes[1];
    const int M  = in_sizes[0] / 128;
    const int P  = (M + CHUNK - 1) / CHUNK;

    // Workspace layout (ints): deg[M] | off[M] | cur[M] | partials[256] | csr[nE]
    int* degi     = (int*)d_ws;
    int* off      = degi + M;
    int* cur      = off + M;
    int* partials = cur + M;
    int* csr      = partials + 256;
    const size_t needed = ((size_t)3 * M + 256 + (size_t)nE) * sizeof(int);

    if (ws_size >= needed) {
        hipMemsetAsync(degi, 0, (size_t)M * sizeof(int), stream);
        hist_kernel<<<(nE + 255) / 256, 256, 0, stream>>>(dst, degi, nE);
        scan_chunks<<<P, 256, 0, stream>>>(degi, off, partials, M);
        scan_partials<<<1, 64, 0, stream>>>(partials, P);
        add_base<<<(M + 255) / 256, 256, 0, stream>>>(off, cur, partials, M);
        bucket_edges<<<(nE + 255) / 256, 256, 0, stream>>>(src, dst, cur, csr, nE);
        // Atomic-free aggregation straight into d_out (fully overwrites every row).
        aggregate<<<(M + 3) / 4, 256, 0, stream>>>(feat, csr, off, degi, out, M);
    } else {
        // Fallback: fp32 atomic scatter (R1 path).
        hipMemsetAsync(d_out, 0, (size_t)out_size * sizeof(float), stream);
        hipMemsetAsync(degi, 0, (size_t)M * sizeof(int), stream);
        scatter_edges_fb<<<2048, 256, 0, stream>>>(feat, src, dst, out, degi, nE);
    }

    gemm_norm<<<(M + 63) / 64, 256, 0, stream>>>(out, weight, bias, degi, out, M);
}

// Round 3
// 440.419 us; speedup vs baseline: 3.4828x; 1.0545x over previous
//
#include <hip/hip_runtime.h>
#include <hip/hip_bf16.h>

#define CHUNK 1024
typedef unsigned int uint;
typedef unsigned short ushort;

// ---------- CSR build ----------
__global__ void hist_kernel(const int* __restrict__ dst, int* __restrict__ deg, int nE) {
    const int i = (blockIdx.x * blockDim.x + threadIdx.x) * 4;
    if (i + 3 < nE) {
        const int4 d4 = *reinterpret_cast<const int4*>(dst + i);
        atomicAdd(&deg[d4.x], 1);
        atomicAdd(&deg[d4.y], 1);
        atomicAdd(&deg[d4.z], 1);
        atomicAdd(&deg[d4.w], 1);
    } else {
        for (int e = i; e < nE; ++e) atomicAdd(&deg[dst[e]], 1);
    }
}

__global__ __launch_bounds__(256) void scan_chunks(const int* __restrict__ deg,
                                                   int* __restrict__ off,
                                                   int* __restrict__ partials, int N) {
    __shared__ int sums[256];
    const int b = blockIdx.x, t = threadIdx.x;
    const int base = b * CHUNK + t * 4;
    int v[4];
#pragma unroll
    for (int i = 0; i < 4; ++i) v[i] = (base + i < N) ? deg[base + i] : 0;
    const int s = v[0] + v[1] + v[2] + v[3];
    sums[t] = s;
    __syncthreads();
    for (int d = 1; d < 256; d <<= 1) {
        int x = (t >= d) ? sums[t - d] : 0;
        __syncthreads();
        sums[t] += x;
        __syncthreads();
    }
    const int excl = sums[t] - s;
    if (t == 255) partials[b] = sums[255];
    int run = excl;
#pragma unroll
    for (int i = 0; i < 4; ++i) {
        if (base + i < N) off[base + i] = run;
        run += v[i];
    }
}

__global__ void scan_partials(int* partials, int P) {
    if (threadIdx.x == 0 && blockIdx.x == 0) {
        int acc = 0;
        for (int i = 0; i < P; ++i) { int v = partials[i]; partials[i] = acc; acc += v; }
    }
}

__global__ void add_base(int* __restrict__ off, int* __restrict__ cur,
                         const int* __restrict__ partials, int N) {
    int i = blockIdx.x * blockDim.x + threadIdx.x;
    if (i < N) {
        int o = off[i] + partials[i >> 10];
        off[i] = o;
        cur[i] = o;
    }
}

__global__ void bucket_edges(const int* __restrict__ src, const int* __restrict__ dst,
                             int* __restrict__ cur, int* __restrict__ csr, int nE) {
    int e = blockIdx.x * blockDim.x + threadIdx.x;
    if (e < nE) {
        const int d = dst[e];
        const int s = src[e];
        const int pos = atomicAdd(&cur[d], 1);
        __builtin_nontemporal_store(s, &csr[pos]);
    }
}

// ---------- Phase A: h = feat @ W, output bf16 ----------
__global__ __launch_bounds__(256) void gemm_h(const float* __restrict__ feat,
                                              const float* __restrict__ weight,
                                              ushort* __restrict__ h, int M) {
    __shared__ float As[64][68];
    __shared__ float Wc[64][128];
    const int t  = threadIdx.x;
    const int tx = t & 15;
    const int ty = t >> 4;
    const int row0 = blockIdx.x * 64;

    float acc[4][8];
#pragma unroll
    for (int i = 0; i < 4; ++i)
#pragma unroll
        for (int j = 0; j < 8; ++j) acc[i][j] = 0.0f;

    for (int c = 0; c < 2; ++c) {
        if (c) __syncthreads();
        {
            const int k4 = (t & 15) * 4;
            const int rbase = t >> 4;
#pragma unroll
            for (int p = 0; p < 4; ++p) {
                const int rr = rbase + p * 16;
                const int grow = row0 + rr;
                float4 v = make_float4(0.f, 0.f, 0.f, 0.f);
                if (grow < M)
                    v = *reinterpret_cast<const float4*>(&feat[(size_t)grow * 128 + c * 64 + k4]);
                *reinterpret_cast<float4*>(&As[rr][k4]) = v;
            }
        }
        {
#pragma unroll
            for (int p = 0; p < 8; ++p) {
                const int idx = (p * 256 + t) * 4;
                const int kk = idx >> 7;
                const int j = idx & 127;
                *reinterpret_cast<float4*>(&Wc[kk][j]) =
                    *reinterpret_cast<const float4*>(&weight[(c * 64 + kk) * 128 + j]);
            }
        }
        __syncthreads();

#pragma unroll 8
        for (int k = 0; k < 64; ++k) {
            float a[4];
#pragma unroll
            for (int i = 0; i < 4; ++i) a[i] = As[ty * 4 + i][k];
            const float4 b0 = *reinterpret_cast<const float4*>(&Wc[k][tx * 8 + 0]);
            const float4 b1 = *reinterpret_cast<const float4*>(&Wc[k][tx * 8 + 4]);
            const float b[8] = {b0.x, b0.y, b0.z, b0.w, b1.x, b1.y, b1.z, b1.w};
#pragma unroll
            for (int i = 0; i < 4; ++i)
#pragma unroll
                for (int j = 0; j < 8; ++j)
                    acc[i][j] = fmaf(a[i], b[j], acc[i][j]);
        }
    }

#pragma unroll
    for (int i = 0; i < 4; ++i) {
        const int grow = row0 + ty * 4 + i;
        if (grow < M) {
            union { ushort u16[8]; uint4 v; } pk;
#pragma unroll
            for (int j = 0; j < 8; ++j) {
                const uint u = __float_as_uint(acc[i][j]);
                pk.u16[j] = (ushort)((u + 0x7fffu + ((u >> 16) & 1u)) >> 16);  // RNE to bf16
            }
            *reinterpret_cast<uint4*>(&h[(size_t)grow * 128 + tx * 8]) = pk.v;
        }
    }
}

// ---------- Phase B: out[n] = (sum_{s in N(n)} h[s]) * rsqrt(max(deg,1)) + bias ----------
// One wave per node. Half-wave split: lanes 0-31 take even edges, 32-63 odd.
// Each lane covers 4 columns (bf16x4 = 8B load), fp32 accumulate, shfl-merge halves.
__global__ __launch_bounds__(256) void aggregate_h(const ushort* __restrict__ h,
                                                   const int* __restrict__ csr,
                                                   const int* __restrict__ off,
                                                   const int* __restrict__ deg,
                                                   const float* __restrict__ bias,
                                                   float* __restrict__ out, int N) {
    const int node = (blockIdx.x * blockDim.x + threadIdx.x) >> 6;
    if (node >= N) return;
    const int lane = threadIdx.x & 63;
    const int half = lane >> 5;
    const int sub  = lane & 31;
    const int start = off[node];
    const int cnt   = deg[node];
    const int end   = start + cnt;

    float ax = 0.f, ay = 0.f, az = 0.f, aw = 0.f;

    int j = start;
    for (; j + 7 < end; j += 8) {
        const int s0 = csr[j + 0 + half];
        const int s1 = csr[j + 2 + half];
        const int s2 = csr[j + 4 + half];
        const int s3 = csr[j + 6 + half];
        const uint2 r0 = *reinterpret_cast<const uint2*>(h + (size_t)s0 * 128 + sub * 4);
        const uint2 r1 = *reinterpret_cast<const uint2*>(h + (size_t)s1 * 128 + sub * 4);
        const uint2 r2 = *reinterpret_cast<const uint2*>(h + (size_t)s2 * 128 + sub * 4);
        const uint2 r3 = *reinterpret_cast<const uint2*>(h + (size_t)s3 * 128 + sub * 4);
        ax += __uint_as_float((r0.x & 0xffffu) << 16) + __uint_as_float((r1.x & 0xffffu) << 16)
            + __uint_as_float((r2.x & 0xffffu) << 16) + __uint_as_float((r3.x & 0xffffu) << 16);
        ay += __uint_as_float(r0.x & 0xffff0000u) + __uint_as_float(r1.x & 0xffff0000u)
            + __uint_as_float(r2.x & 0xffff0000u) + __uint_as_float(r3.x & 0xffff0000u);
        az += __uint_as_float((r0.y & 0xffffu) << 16) + __uint_as_float((r1.y & 0xffffu) << 16)
            + __uint_as_float((r2.y & 0xffffu) << 16) + __uint_as_float((r3.y & 0xffffu) << 16);
        aw += __uint_as_float(r0.y & 0xffff0000u) + __uint_as_float(r1.y & 0xffff0000u)
            + __uint_as_float(r2.y & 0xffff0000u) + __uint_as_float(r3.y & 0xffff0000u);
    }
    for (j += half; j < end; j += 2) {
        const int s = csr[j];
        const uint2 r = *reinterpret_cast<const uint2*>(h + (size_t)s * 128 + sub * 4);
        ax += __uint_as_float((r.x & 0xffffu) << 16);
        ay += __uint_as_float(r.x & 0xffff0000u);
        az += __uint_as_float((r.y & 0xffffu) << 16);
        aw += __uint_as_float(r.y & 0xffff0000u);
    }

    // Merge the two half-wave accumulators (same columns, alternate edges).
    ax += __shfl_xor(ax, 32, 64);
    ay += __shfl_xor(ay, 32, 64);
    az += __shfl_xor(az, 32, 64);
    aw += __shfl_xor(aw, 32, 64);

    if (half == 0) {
        const float nm = rsqrtf(fmaxf((float)cnt, 1.0f));
        const float4 b = *reinterpret_cast<const float4*>(bias + sub * 4);
        float4 o;
        o.x = fmaf(ax, nm, b.x);
        o.y = fmaf(ay, nm, b.y);
        o.z = fmaf(az, nm, b.z);
        o.w = fmaf(aw, nm, b.w);
        *reinterpret_cast<float4*>(out + (size_t)node * 128 + sub * 4) = o;
    }
}

// ---------- Fallback path (ws too small for bf16 h): R2 structure ----------
__global__ __launch_bounds__(256) void aggregate_f32(const float* __restrict__ feat,
                                                     const int* __restrict__ csr,
                                                     const int* __restrict__ off,
                                                     const int* __restrict__ deg,
                                                     float* __restrict__ out, int N) {
    const int node = (blockIdx.x * blockDim.x + threadIdx.x) >> 6;
    if (node >= N) return;
    const int lane = threadIdx.x & 63;
    const int start = off[node];
    const int end   = start + deg[node];
    const float2* feat2 = reinterpret_cast<const float2*>(feat);
    float ax = 0.0f, ay = 0.0f;
    for (int j = start; j < end; ++j) {
        const float2 v = feat2[(size_t)csr[j] * 64 + lane];
        ax += v.x;
        ay += v.y;
    }
    reinterpret_cast<float2*>(out)[(size_t)node * 64 + lane] = make_float2(ax, ay);
}

__global__ __launch_bounds__(256) void gemm_norm(const float* agg,
                                                 const float* __restrict__ weight,
                                                 const float* __restrict__ bias,
                                                 const int* __restrict__ deg,
                                                 float* out, int M) {
    __shared__ float As[64][68];
    __shared__ float Wc[64][128];
    const int t  = threadIdx.x;
    const int tx = t & 15;
    const int ty = t >> 4;
    const int row0 = blockIdx.x * 64;
    float acc[4][8];
#pragma unroll
    for (int i = 0; i < 4; ++i)
#pragma unroll
        for (int j = 0; j < 8; ++j) acc[i][j] = 0.0f;
    for (int c = 0; c < 2; ++c) {
        if (c) __syncthreads();
        {
            const int k4 = (t & 15) * 4;
            const int rbase = t >> 4;
#pragma unroll
            for (int p = 0; p < 4; ++p) {
                const int rr = rbase + p * 16;
                const int grow = row0 + rr;
                float4 v = make_float4(0.f, 0.f, 0.f, 0.f);
                if (grow < M)
                    v = *reinterpret_cast<const float4*>(&agg[(size_t)grow * 128 + c * 64 + k4]);
                *reinterpret_cast<float4*>(&As[rr][k4]) = v;
            }
        }
        {
#pragma unroll
            for (int p = 0; p < 8; ++p) {
                const int idx = (p * 256 + t) * 4;
                const int kk = idx >> 7;
                const int j = idx & 127;
                *reinterpret_cast<float4*>(&Wc[kk][j]) =
                    *reinterpret_cast<const float4*>(&weight[(c * 64 + kk) * 128 + j]);
            }
        }
        __syncthreads();
#pragma unroll 8
        for (int k = 0; k < 64; ++k) {
            float a[4];
#pragma unroll
            for (int i = 0; i < 4; ++i) a[i] = As[ty * 4 + i][k];
            const float4 b0 = *reinterpret_cast<const float4*>(&Wc[k][tx * 8 + 0]);
            const float4 b1 = *reinterpret_cast<const float4*>(&Wc[k][tx * 8 + 4]);
            const float b[8] = {b0.x, b0.y, b0.z, b0.w, b1.x, b1.y, b1.z, b1.w};
#pragma unroll
            for (int i = 0; i < 4; ++i)
#pragma unroll
                for (int j = 0; j < 8; ++j)
                    acc[i][j] = fmaf(a[i], b[j], acc[i][j]);
        }
    }
    float bcol[8];
#pragma unroll
    for (int j = 0; j < 8; ++j) bcol[j] = bias[tx * 8 + j];
#pragma unroll
    for (int i = 0; i < 4; ++i) {
        const int grow = row0 + ty * 4 + i;
        if (grow < M) {
            const float nm = rsqrtf(fmaxf((float)deg[grow], 1.0f));
            float4 o0, o1;
            o0.x = fmaf(acc[i][0], nm, bcol[0]);
            o0.y = fmaf(acc[i][1], nm, bcol[1]);
            o0.z = fmaf(acc[i][2], nm, bcol[2]);
            o0.w = fmaf(acc[i][3], nm, bcol[3]);
            o1.x = fmaf(acc[i][4], nm, bcol[4]);
            o1.y = fmaf(acc[i][5], nm, bcol[5]);
            o1.z = fmaf(acc[i][6], nm, bcol[6]);
            o1.w = fmaf(acc[i][7], nm, bcol[7]);
            *reinterpret_cast<float4*>(&out[(size_t)grow * 128 + tx * 8 + 0]) = o0;
            *reinterpret_cast<float4*>(&out[(size_t)grow * 128 + tx * 8 + 4]) = o1;
        }
    }
}

extern "C" void kernel_launch(void* const* d_in, const int* in_sizes, int n_in,
                              void* d_out, int out_size, void* d_ws, size_t ws_size,
                              hipStream_t stream) {
    const float* feat   = (const float*)d_in[0];
    const int*   src    = (const int*)d_in[1];
    const int*   dst    = (const int*)d_in[2];
    const float* weight = (const float*)d_in[3];
    const float* bias   = (const float*)d_in[4];
    float* out = (float*)d_out;

    const int nE = in_sizes[1];
    const int M  = in_sizes[0] / 128;
    const int P  = (M + CHUNK - 1) / CHUNK;

    // ws layout (ints): deg[M] | off[M] | cur[M] | partials[256] | csr[nE] | h(bf16, 16B-aligned)
    int* degi     = (int*)d_ws;
    int* off      = degi + M;
    int* cur      = off + M;
    int* partials = cur + M;
    int* csr      = partials + 256;
    const size_t csr_bytes = ((size_t)3 * M + 256 + (size_t)nE) * sizeof(int);
    const size_t h_off     = (csr_bytes + 15) & ~(size_t)15;
    ushort* h = (ushort*)((char*)d_ws + h_off);
    const size_t need_big = h_off + (size_t)M * 128 * sizeof(ushort);

    // CSR build (common to both paths)
    hipMemsetAsync(degi, 0, (size_t)M * sizeof(int), stream);
    hist_kernel<<<(nE / 4 + 255) / 256, 256, 0, stream>>>(dst, degi, nE);
    scan_chunks<<<P, 256, 0, stream>>>(degi, off, partials, M);
    scan_partials<<<1, 64, 0, stream>>>(partials, P);
    add_base<<<(M + 255) / 256, 256, 0, stream>>>(off, cur, partials, M);
    bucket_edges<<<(nE + 255) / 256, 256, 0, stream>>>(src, dst, cur, csr, nE);

    if (ws_size >= need_big) {
        // GEMM-first: h = feat @ W (bf16), then fused aggregate+norm+bias.
        gemm_h<<<(M + 63) / 64, 256, 0, stream>>>(feat, weight, h, M);
        aggregate_h<<<(M + 3) / 4, 256, 0, stream>>>(h, csr, off, degi, bias, out, M);
    } else {
        aggregate_f32<<<(M + 3) / 4, 256, 0, stream>>>(feat, csr, off, degi, out, M);
        gemm_norm<<<(M + 63) / 64, 256, 0, stream>>>(out, weight, bias, degi, out, M);
    }
}

// Round 4
// 378.671 us; speedup vs baseline: 4.0508x; 1.1631x over previous
//
#include <hip/hip_runtime.h>
#include <hip/hip_bf16.h>

#define CHUNK 1024
typedef unsigned int uint;
typedef unsigned short ushort;

// ---------- CSR build, XCD-range partitioned ----------
// Block b handles dst range [b&7]; blocks with equal (b&7) land on the same XCD
// (blockIdx%8 round-robin heuristic) so each csr/deg/cur slice is written by one
// XCD only -> lines accumulate fully dirty in that L2, one full-line writeback.
__global__ __launch_bounds__(256) void hist_part(const int* __restrict__ dst,
                                                 int* __restrict__ deg, int nE, int N) {
    const int r  = blockIdx.x & 7;
    const int g  = blockIdx.x >> 3;  // 0..31 within range-group
    const int lo = (int)(((long long)r * N) >> 3);
    const int hi = (int)(((long long)(r + 1) * N) >> 3);
    const int tid = g * 256 + (int)threadIdx.x;  // 0..8191
    const int stride4 = 32 * 256 * 4;
    for (int e4 = tid * 4; e4 < nE; e4 += stride4) {
        if (e4 + 3 < nE) {
            const int4 d4 = *reinterpret_cast<const int4*>(dst + e4);
            if (d4.x >= lo && d4.x < hi) atomicAdd(&deg[d4.x], 1);
            if (d4.y >= lo && d4.y < hi) atomicAdd(&deg[d4.y], 1);
            if (d4.z >= lo && d4.z < hi) atomicAdd(&deg[d4.z], 1);
            if (d4.w >= lo && d4.w < hi) atomicAdd(&deg[d4.w], 1);
        } else {
            for (int e = e4; e < nE; ++e) {
                const int d = dst[e];
                if (d >= lo && d < hi) atomicAdd(&deg[d], 1);
            }
        }
    }
}

__global__ __launch_bounds__(256) void bucket_part(const int* __restrict__ src,
                                                   const int* __restrict__ dst,
                                                   int* __restrict__ cur,
                                                   int* __restrict__ csr, int nE, int N) {
    const int r  = blockIdx.x & 7;
    const int g  = blockIdx.x >> 3;
    const int lo = (int)(((long long)r * N) >> 3);
    const int hi = (int)(((long long)(r + 1) * N) >> 3);
    const int tid = g * 256 + (int)threadIdx.x;
    const int stride4 = 32 * 256 * 4;
    for (int e4 = tid * 4; e4 < nE; e4 += stride4) {
        if (e4 + 3 < nE) {
            const int4 d4 = *reinterpret_cast<const int4*>(dst + e4);
            const bool m0 = (d4.x >= lo && d4.x < hi);
            const bool m1 = (d4.y >= lo && d4.y < hi);
            const bool m2 = (d4.z >= lo && d4.z < hi);
            const bool m3 = (d4.w >= lo && d4.w < hi);
            if (m0 | m1 | m2 | m3) {
                const int4 s4 = *reinterpret_cast<const int4*>(src + e4);
                int p0, p1, p2, p3;  // independent atomics -> overlapped latency
                if (m0) p0 = atomicAdd(&cur[d4.x], 1);
                if (m1) p1 = atomicAdd(&cur[d4.y], 1);
                if (m2) p2 = atomicAdd(&cur[d4.z], 1);
                if (m3) p3 = atomicAdd(&cur[d4.w], 1);
                if (m0) csr[p0] = s4.x;
                if (m1) csr[p1] = s4.y;
                if (m2) csr[p2] = s4.z;
                if (m3) csr[p3] = s4.w;
            }
        } else {
            for (int e = e4; e < nE; ++e) {
                const int d = dst[e];
                if (d >= lo && d < hi) {
                    const int pos = atomicAdd(&cur[d], 1);
                    csr[pos] = src[e];
                }
            }
        }
    }
}

__global__ __launch_bounds__(256) void scan_chunks(const int* __restrict__ deg,
                                                   int* __restrict__ off,
                                                   int* __restrict__ partials, int N) {
    __shared__ int sums[256];
    const int b = blockIdx.x, t = threadIdx.x;
    const int base = b * CHUNK + t * 4;
    int v[4];
#pragma unroll
    for (int i = 0; i < 4; ++i) v[i] = (base + i < N) ? deg[base + i] : 0;
    const int s = v[0] + v[1] + v[2] + v[3];
    sums[t] = s;
    __syncthreads();
    for (int d = 1; d < 256; d <<= 1) {
        int x = (t >= d) ? sums[t - d] : 0;
        __syncthreads();
        sums[t] += x;
        __syncthreads();
    }
    const int excl = sums[t] - s;
    if (t == 255) partials[b] = sums[255];
    int run = excl;
#pragma unroll
    for (int i = 0; i < 4; ++i) {
        if (base + i < N) off[base + i] = run;
        run += v[i];
    }
}

__global__ void scan_partials(int* partials, int P) {
    if (threadIdx.x == 0 && blockIdx.x == 0) {
        int acc = 0;
        for (int i = 0; i < P; ++i) { int v = partials[i]; partials[i] = acc; acc += v; }
    }
}

__global__ void add_base(int* __restrict__ off, int* __restrict__ cur,
                         const int* __restrict__ partials, int N) {
    int i = blockIdx.x * blockDim.x + threadIdx.x;
    if (i < N) {
        int o = off[i] + partials[i >> 10];
        off[i] = o;
        cur[i] = o;
    }
}

// ---------- Phase A: h = feat @ W, output bf16 ----------
__global__ __launch_bounds__(256) void gemm_h(const float* __restrict__ feat,
                                              const float* __restrict__ weight,
                                              ushort* __restrict__ h, int M) {
    __shared__ float As[64][68];
    __shared__ float Wc[64][128];
    const int t  = threadIdx.x;
    const int tx = t & 15;
    const int ty = t >> 4;
    const int row0 = blockIdx.x * 64;

    float acc[4][8];
#pragma unroll
    for (int i = 0; i < 4; ++i)
#pragma unroll
        for (int j = 0; j < 8; ++j) acc[i][j] = 0.0f;

    for (int c = 0; c < 2; ++c) {
        if (c) __syncthreads();
        {
            const int k4 = (t & 15) * 4;
            const int rbase = t >> 4;
#pragma unroll
            for (int p = 0; p < 4; ++p) {
                const int rr = rbase + p * 16;
                const int grow = row0 + rr;
                float4 v = make_float4(0.f, 0.f, 0.f, 0.f);
                if (grow < M)
                    v = *reinterpret_cast<const float4*>(&feat[(size_t)grow * 128 + c * 64 + k4]);
                *reinterpret_cast<float4*>(&As[rr][k4]) = v;
            }
        }
        {
#pragma unroll
            for (int p = 0; p < 8; ++p) {
                const int idx = (p * 256 + t) * 4;
                const int kk = idx >> 7;
                const int j = idx & 127;
                *reinterpret_cast<float4*>(&Wc[kk][j]) =
                    *reinterpret_cast<const float4*>(&weight[(c * 64 + kk) * 128 + j]);
            }
        }
        __syncthreads();

#pragma unroll 8
        for (int k = 0; k < 64; ++k) {
            float a[4];
#pragma unroll
            for (int i = 0; i < 4; ++i) a[i] = As[ty * 4 + i][k];
            const float4 b0 = *reinterpret_cast<const float4*>(&Wc[k][tx * 8 + 0]);
            const float4 b1 = *reinterpret_cast<const float4*>(&Wc[k][tx * 8 + 4]);
            const float b[8] = {b0.x, b0.y, b0.z, b0.w, b1.x, b1.y, b1.z, b1.w};
#pragma unroll
            for (int i = 0; i < 4; ++i)
#pragma unroll
                for (int j = 0; j < 8; ++j)
                    acc[i][j] = fmaf(a[i], b[j], acc[i][j]);
        }
    }

#pragma unroll
    for (int i = 0; i < 4; ++i) {
        const int grow = row0 + ty * 4 + i;
        if (grow < M) {
            union { ushort u16[8]; uint4 v; } pk;
#pragma unroll
            for (int j = 0; j < 8; ++j) {
                const uint u = __float_as_uint(acc[i][j]);
                pk.u16[j] = (ushort)((u + 0x7fffu + ((u >> 16) & 1u)) >> 16);  // RNE to bf16
            }
            *reinterpret_cast<uint4*>(&h[(size_t)grow * 128 + tx * 8]) = pk.v;
        }
    }
}

// ---------- Phase B: out[n] = (sum h[s]) * rsqrt(max(deg,1)) + bias ----------
__global__ __launch_bounds__(256) void aggregate_h(const ushort* __restrict__ h,
                                                   const int* __restrict__ csr,
                                                   const int* __restrict__ off,
                                                   const int* __restrict__ deg,
                                                   const float* __restrict__ bias,
                                                   float* __restrict__ out, int N) {
    const int node = (blockIdx.x * blockDim.x + threadIdx.x) >> 6;
    if (node >= N) return;
    const int lane = threadIdx.x & 63;
    const int half = lane >> 5;
    const int sub  = lane & 31;
    const int start = off[node];
    const int cnt   = deg[node];
    const int end   = start + cnt;

    float ax = 0.f, ay = 0.f, az = 0.f, aw = 0.f;

    int j = start;
    for (; j + 7 < end; j += 8) {
        const int s0 = csr[j + 0 + half];
        const int s1 = csr[j + 2 + half];
        const int s2 = csr[j + 4 + half];
        const int s3 = csr[j + 6 + half];
        const uint2 r0 = *reinterpret_cast<const uint2*>(h + (size_t)s0 * 128 + sub * 4);
        const uint2 r1 = *reinterpret_cast<const uint2*>(h + (size_t)s1 * 128 + sub * 4);
        const uint2 r2 = *reinterpret_cast<const uint2*>(h + (size_t)s2 * 128 + sub * 4);
        const uint2 r3 = *reinterpret_cast<const uint2*>(h + (size_t)s3 * 128 + sub * 4);
        ax += __uint_as_float((r0.x & 0xffffu) << 16) + __uint_as_float((r1.x & 0xffffu) << 16)
            + __uint_as_float((r2.x & 0xffffu) << 16) + __uint_as_float((r3.x & 0xffffu) << 16);
        ay += __uint_as_float(r0.x & 0xffff0000u) + __uint_as_float(r1.x & 0xffff0000u)
            + __uint_as_float(r2.x & 0xffff0000u) + __uint_as_float(r3.x & 0xffff0000u);
        az += __uint_as_float((r0.y & 0xffffu) << 16) + __uint_as_float((r1.y & 0xffffu) << 16)
            + __uint_as_float((r2.y & 0xffffu) << 16) + __uint_as_float((r3.y & 0xffffu) << 16);
        aw += __uint_as_float(r0.y & 0xffff0000u) + __uint_as_float(r1.y & 0xffff0000u)
            + __uint_as_float(r2.y & 0xffff0000u) + __uint_as_float(r3.y & 0xffff0000u);
    }
    for (j += half; j < end; j += 2) {
        const int s = csr[j];
        const uint2 r = *reinterpret_cast<const uint2*>(h + (size_t)s * 128 + sub * 4);
        ax += __uint_as_float((r.x & 0xffffu) << 16);
        ay += __uint_as_float(r.x & 0xffff0000u);
        az += __uint_as_float((r.y & 0xffffu) << 16);
        aw += __uint_as_float(r.y & 0xffff0000u);
    }

    ax += __shfl_xor(ax, 32, 64);
    ay += __shfl_xor(ay, 32, 64);
    az += __shfl_xor(az, 32, 64);
    aw += __shfl_xor(aw, 32, 64);

    if (half == 0) {
        const float nm = rsqrtf(fmaxf((float)cnt, 1.0f));
        const float4 b = *reinterpret_cast<const float4*>(bias + sub * 4);
        float4 o;
        o.x = fmaf(ax, nm, b.x);
        o.y = fmaf(ay, nm, b.y);
        o.z = fmaf(az, nm, b.z);
        o.w = fmaf(aw, nm, b.w);
        *reinterpret_cast<float4*>(out + (size_t)node * 128 + sub * 4) = o;
    }
}

// ---------- Fallback path (ws too small for bf16 h) ----------
__global__ __launch_bounds__(256) void aggregate_f32(const float* __restrict__ feat,
                                                     const int* __restrict__ csr,
                                                     const int* __restrict__ off,
                                                     const int* __restrict__ deg,
                                                     float* __restrict__ out, int N) {
    const int node = (blockIdx.x * blockDim.x + threadIdx.x) >> 6;
    if (node >= N) return;
    const int lane = threadIdx.x & 63;
    const int start = off[node];
    const int end   = start + deg[node];
    const float2* feat2 = reinterpret_cast<const float2*>(feat);
    float ax = 0.0f, ay = 0.0f;
    for (int j = start; j < end; ++j) {
        const float2 v = feat2[(size_t)csr[j] * 64 + lane];
        ax += v.x;
        ay += v.y;
    }
    reinterpret_cast<float2*>(out)[(size_t)node * 64 + lane] = make_float2(ax, ay);
}

__global__ __launch_bounds__(256) void gemm_norm(const float* agg,
                                                 const float* __restrict__ weight,
                                                 const float* __restrict__ bias,
                                                 const int* __restrict__ deg,
                                                 float* out, int M) {
    __shared__ float As[64][68];
    __shared__ float Wc[64][128];
    const int t  = threadIdx.x;
    const int tx = t & 15;
    const int ty = t >> 4;
    const int row0 = blockIdx.x * 64;
    float acc[4][8];
#pragma unroll
    for (int i = 0; i < 4; ++i)
#pragma unroll
        for (int j = 0; j < 8; ++j) acc[i][j] = 0.0f;
    for (int c = 0; c < 2; ++c) {
        if (c) __syncthreads();
        {
            const int k4 = (t & 15) * 4;
            const int rbase = t >> 4;
#pragma unroll
            for (int p = 0; p < 4; ++p) {
                const int rr = rbase + p * 16;
                const int grow = row0 + rr;
                float4 v = make_float4(0.f, 0.f, 0.f, 0.f);
                if (grow < M)
                    v = *reinterpret_cast<const float4*>(&agg[(size_t)grow * 128 + c * 64 + k4]);
                *reinterpret_cast<float4*>(&As[rr][k4]) = v;
            }
        }
        {
#pragma unroll
            for (int p = 0; p < 8; ++p) {
                const int idx = (p * 256 + t) * 4;
                const int kk = idx >> 7;
                const int j = idx & 127;
                *reinterpret_cast<float4*>(&Wc[kk][j]) =
                    *reinterpret_cast<const float4*>(&weight[(c * 64 + kk) * 128 + j]);
            }
        }
        __syncthreads();
#pragma unroll 8
        for (int k = 0; k < 64; ++k) {
            float a[4];
#pragma unroll
            for (int i = 0; i < 4; ++i) a[i] = As[ty * 4 + i][k];
            const float4 b0 = *reinterpret_cast<const float4*>(&Wc[k][tx * 8 + 0]);
            const float4 b1 = *reinterpret_cast<const float4*>(&Wc[k][tx * 8 + 4]);
            const float b[8] = {b0.x, b0.y, b0.z, b0.w, b1.x, b1.y, b1.z, b1.w};
#pragma unroll
            for (int i = 0; i < 4; ++i)
#pragma unroll
                for (int j = 0; j < 8; ++j)
                    acc[i][j] = fmaf(a[i], b[j], acc[i][j]);
        }
    }
    float bcol[8];
#pragma unroll
    for (int j = 0; j < 8; ++j) bcol[j] = bias[tx * 8 + j];
#pragma unroll
    for (int i = 0; i < 4; ++i) {
        const int grow = row0 + ty * 4 + i;
        if (grow < M) {
            const float nm = rsqrtf(fmaxf((float)deg[grow], 1.0f));
            float4 o0, o1;
            o0.x = fmaf(acc[i][0], nm, bcol[0]);
            o0.y = fmaf(acc[i][1], nm, bcol[1]);
            o0.z = fmaf(acc[i][2], nm, bcol[2]);
            o0.w = fmaf(acc[i][3], nm, bcol[3]);
            o1.x = fmaf(acc[i][4], nm, bcol[4]);
            o1.y = fmaf(acc[i][5], nm, bcol[5]);
            o1.z = fmaf(acc[i][6], nm, bcol[6]);
            o1.w = fmaf(acc[i][7], nm, bcol[7]);
            *reinterpret_cast<float4*>(&out[(size_t)grow * 128 + tx * 8 + 0]) = o0;
            *reinterpret_cast<float4*>(&out[(size_t)grow * 128 + tx * 8 + 4]) = o1;
        }
    }
}

extern "C" void kernel_launch(void* const* d_in, const int* in_sizes, int n_in,
                              void* d_out, int out_size, void* d_ws, size_t ws_size,
                              hipStream_t stream) {
    const float* feat   = (const float*)d_in[0];
    const int*   src    = (const int*)d_in[1];
    const int*   dst    = (const int*)d_in[2];
    const float* weight = (const float*)d_in[3];
    const float* bias   = (const float*)d_in[4];
    float* out = (float*)d_out;

    const int nE = in_sizes[1];
    const int M  = in_sizes[0] / 128;
    const int P  = (M + CHUNK - 1) / CHUNK;

    // ws layout (ints): deg[M] | off[M] | cur[M] | partials[256] | csr[nE] | h(bf16, 16B-aligned)
    int* degi     = (int*)d_ws;
    int* off      = degi + M;
    int* cur      = off + M;
    int* partials = cur + M;
    int* csr      = partials + 256;
    const size_t csr_bytes = ((size_t)3 * M + 256 + (size_t)nE) * sizeof(int);
    const size_t h_off     = (csr_bytes + 15) & ~(size_t)15;
    ushort* h = (ushort*)((char*)d_ws + h_off);
    const size_t need_big = h_off + (size_t)M * 128 * sizeof(ushort);

    // CSR build (XCD-range partitioned hist + bucket)
    hipMemsetAsync(degi, 0, (size_t)M * sizeof(int), stream);
    hist_part<<<256, 256, 0, stream>>>(dst, degi, nE, M);
    scan_chunks<<<P, 256, 0, stream>>>(degi, off, partials, M);
    scan_partials<<<1, 64, 0, stream>>>(partials, P);
    add_base<<<(M + 255) / 256, 256, 0, stream>>>(off, cur, partials, M);
    bucket_part<<<256, 256, 0, stream>>>(src, dst, cur, csr, nE, M);

    if (ws_size >= need_big) {
        gemm_h<<<(M + 63) / 64, 256, 0, stream>>>(feat, weight, h, M);
        aggregate_h<<<(M + 3) / 4, 256, 0, stream>>>(h, csr, off, degi, bias, out, M);
    } else {
        aggregate_f32<<<(M + 3) / 4, 256, 0, stream>>>(feat, csr, off, degi, out, M);
        gemm_norm<<<(M + 63) / 64, 256, 0, stream>>>(out, weight, bias, degi, out, M);
    }
}

// Round 5
// 371.514 us; speedup vs baseline: 4.1288x; 1.0193x over previous
//
#include <hip/hip_runtime.h>
#include <hip/hip_bf16.h>

#define CHUNK 1024
#define GROUPS 256            // blocks per dst-range (grid = 8*GROUPS)
typedef unsigned int uint;
typedef unsigned short ushort;

// ---------- CSR build, XCD-range partitioned ----------
// Block b handles dst range [b&7]; blocks with equal (b&7) land on the same XCD
// (blockIdx%8 round-robin heuristic) so each csr/deg/cur slice is written by one
// XCD only -> lines accumulate fully dirty in that L2, one full-line writeback.
__global__ __launch_bounds__(256) void hist_part(const int* __restrict__ dst,
                                                 int* __restrict__ deg, int nE, int N) {
    const int r  = blockIdx.x & 7;
    const int g  = blockIdx.x >> 3;  // 0..GROUPS-1 within range-group
    const int lo = (int)(((long long)r * N) >> 3);
    const int hi = (int)(((long long)(r + 1) * N) >> 3);
    const int tid = g * 256 + (int)threadIdx.x;
    const int stride4 = GROUPS * 256 * 4;
    for (int e4 = tid * 4; e4 < nE; e4 += stride4) {
        if (e4 + 3 < nE) {
            const int4 d4 = *reinterpret_cast<const int4*>(dst + e4);
            if (d4.x >= lo && d4.x < hi) atomicAdd(&deg[d4.x], 1);
            if (d4.y >= lo && d4.y < hi) atomicAdd(&deg[d4.y], 1);
            if (d4.z >= lo && d4.z < hi) atomicAdd(&deg[d4.z], 1);
            if (d4.w >= lo && d4.w < hi) atomicAdd(&deg[d4.w], 1);
        } else {
            for (int e = e4; e < nE; ++e) {
                const int d = dst[e];
                if (d >= lo && d < hi) atomicAdd(&deg[d], 1);
            }
        }
    }
}

__global__ __launch_bounds__(256) void bucket_part(const int* __restrict__ src,
                                                   const int* __restrict__ dst,
                                                   int* __restrict__ cur,
                                                   int* __restrict__ csr, int nE, int N) {
    const int r  = blockIdx.x & 7;
    const int g  = blockIdx.x >> 3;
    const int lo = (int)(((long long)r * N) >> 3);
    const int hi = (int)(((long long)(r + 1) * N) >> 3);
    const int tid = g * 256 + (int)threadIdx.x;
    const int stride4 = GROUPS * 256 * 4;
    for (int e4 = tid * 4; e4 < nE; e4 += stride4) {
        if (e4 + 3 < nE) {
            const int4 d4 = *reinterpret_cast<const int4*>(dst + e4);
            const bool m0 = (d4.x >= lo && d4.x < hi);
            const bool m1 = (d4.y >= lo && d4.y < hi);
            const bool m2 = (d4.z >= lo && d4.z < hi);
            const bool m3 = (d4.w >= lo && d4.w < hi);
            if (m0 | m1 | m2 | m3) {
                const int4 s4 = *reinterpret_cast<const int4*>(src + e4);
                int p0, p1, p2, p3;  // independent atomics -> overlapped latency
                if (m0) p0 = atomicAdd(&cur[d4.x], 1);
                if (m1) p1 = atomicAdd(&cur[d4.y], 1);
                if (m2) p2 = atomicAdd(&cur[d4.z], 1);
                if (m3) p3 = atomicAdd(&cur[d4.w], 1);
                if (m0) csr[p0] = s4.x;
                if (m1) csr[p1] = s4.y;
                if (m2) csr[p2] = s4.z;
                if (m3) csr[p3] = s4.w;
            }
        } else {
            for (int e = e4; e < nE; ++e) {
                const int d = dst[e];
                if (d >= lo && d < hi) {
                    const int pos = atomicAdd(&cur[d], 1);
                    csr[pos] = src[e];
                }
            }
        }
    }
}

__global__ __launch_bounds__(256) void scan_chunks(const int* __restrict__ deg,
                                                   int* __restrict__ off,
                                                   int* __restrict__ partials, int N) {
    __shared__ int sums[256];
    const int b = blockIdx.x, t = threadIdx.x;
    const int base = b * CHUNK + t * 4;
    int v[4];
#pragma unroll
    for (int i = 0; i < 4; ++i) v[i] = (base + i < N) ? deg[base + i] : 0;
    const int s = v[0] + v[1] + v[2] + v[3];
    sums[t] = s;
    __syncthreads();
    for (int d = 1; d < 256; d <<= 1) {
        int x = (t >= d) ? sums[t - d] : 0;
        __syncthreads();
        sums[t] += x;
        __syncthreads();
    }
    const int excl = sums[t] - s;
    if (t == 255) partials[b] = sums[255];
    int run = excl;
#pragma unroll
    for (int i = 0; i < 4; ++i) {
        if (base + i < N) off[base + i] = run;
        run += v[i];
    }
}

__global__ void scan_partials(int* partials, int P) {
    if (threadIdx.x == 0 && blockIdx.x == 0) {
        int acc = 0;
        for (int i = 0; i < P; ++i) { int v = partials[i]; partials[i] = acc; acc += v; }
    }
}

__global__ void add_base(int* __restrict__ off, int* __restrict__ cur,
                         const int* __restrict__ partials, int N) {
    int i = blockIdx.x * blockDim.x + threadIdx.x;
    if (i < N) {
        int o = off[i] + partials[i >> 10];
        off[i] = o;
        cur[i] = o;
    }
}

// ---------- Phase A: h = feat @ W, output bf16 ----------
__global__ __launch_bounds__(256) void gemm_h(const float* __restrict__ feat,
                                              const float* __restrict__ weight,
                                              ushort* __restrict__ h, int M) {
    __shared__ float As[64][68];
    __shared__ float Wc[64][128];
    const int t  = threadIdx.x;
    const int tx = t & 15;
    const int ty = t >> 4;
    const int row0 = blockIdx.x * 64;

    float acc[4][8];
#pragma unroll
    for (int i = 0; i < 4; ++i)
#pragma unroll
        for (int j = 0; j < 8; ++j) acc[i][j] = 0.0f;

    for (int c = 0; c < 2; ++c) {
        if (c) __syncthreads();
        {
            const int k4 = (t & 15) * 4;
            const int rbase = t >> 4;
#pragma unroll
            for (int p = 0; p < 4; ++p) {
                const int rr = rbase + p * 16;
                const int grow = row0 + rr;
                float4 v = make_float4(0.f, 0.f, 0.f, 0.f);
                if (grow < M)
                    v = *reinterpret_cast<const float4*>(&feat[(size_t)grow * 128 + c * 64 + k4]);
                *reinterpret_cast<float4*>(&As[rr][k4]) = v;
            }
        }
        {
#pragma unroll
            for (int p = 0; p < 8; ++p) {
                const int idx = (p * 256 + t) * 4;
                const int kk = idx >> 7;
                const int j = idx & 127;
                *reinterpret_cast<float4*>(&Wc[kk][j]) =
                    *reinterpret_cast<const float4*>(&weight[(c * 64 + kk) * 128 + j]);
            }
        }
        __syncthreads();

#pragma unroll 8
        for (int k = 0; k < 64; ++k) {
            float a[4];
#pragma unroll
            for (int i = 0; i < 4; ++i) a[i] = As[ty * 4 + i][k];
            const float4 b0 = *reinterpret_cast<const float4*>(&Wc[k][tx * 8 + 0]);
            const float4 b1 = *reinterpret_cast<const float4*>(&Wc[k][tx * 8 + 4]);
            const float b[8] = {b0.x, b0.y, b0.z, b0.w, b1.x, b1.y, b1.z, b1.w};
#pragma unroll
            for (int i = 0; i < 4; ++i)
#pragma unroll
                for (int j = 0; j < 8; ++j)
                    acc[i][j] = fmaf(a[i], b[j], acc[i][j]);
        }
    }

#pragma unroll
    for (int i = 0; i < 4; ++i) {
        const int grow = row0 + ty * 4 + i;
        if (grow < M) {
            union { ushort u16[8]; uint4 v; } pk;
#pragma unroll
            for (int j = 0; j < 8; ++j) {
                const uint u = __float_as_uint(acc[i][j]);
                pk.u16[j] = (ushort)((u + 0x7fffu + ((u >> 16) & 1u)) >> 16);  // RNE to bf16
            }
            *reinterpret_cast<uint4*>(&h[(size_t)grow * 128 + tx * 8]) = pk.v;
        }
    }
}

// ---------- Phase B: out[n] = (sum h[s]) * rsqrt(max(deg,1)) + bias ----------
// One wave per node; lanes 0-31 even edges, 32-63 odd. 16 edges/iter => 8
// outstanding uint2 gathers per lane to hide L3 latency.
__global__ __launch_bounds__(256) void aggregate_h(const ushort* __restrict__ h,
                                                   const int* __restrict__ csr,
                                                   const int* __restrict__ off,
                                                   const int* __restrict__ deg,
                                                   const float* __restrict__ bias,
                                                   float* __restrict__ out, int N) {
    const int node = (blockIdx.x * blockDim.x + threadIdx.x) >> 6;
    if (node >= N) return;
    const int lane = threadIdx.x & 63;
    const int half = lane >> 5;
    const int sub  = lane & 31;
    const int start = off[node];
    const int cnt   = deg[node];
    const int end   = start + cnt;

    float ax = 0.f, ay = 0.f, az = 0.f, aw = 0.f;

    int j = start;
    for (; j + 15 < end; j += 16) {
        int s[8];
#pragma unroll
        for (int k = 0; k < 8; ++k) s[k] = csr[j + 2 * k + half];
        uint2 r[8];
#pragma unroll
        for (int k = 0; k < 8; ++k)
            r[k] = *reinterpret_cast<const uint2*>(h + (size_t)s[k] * 128 + sub * 4);
#pragma unroll
        for (int k = 0; k < 8; ++k) {
            ax += __uint_as_float((r[k].x & 0xffffu) << 16);
            ay += __uint_as_float(r[k].x & 0xffff0000u);
            az += __uint_as_float((r[k].y & 0xffffu) << 16);
            aw += __uint_as_float(r[k].y & 0xffff0000u);
        }
    }
    for (; j + 7 < end; j += 8) {
        int s[4];
#pragma unroll
        for (int k = 0; k < 4; ++k) s[k] = csr[j + 2 * k + half];
        uint2 r[4];
#pragma unroll
        for (int k = 0; k < 4; ++k)
            r[k] = *reinterpret_cast<const uint2*>(h + (size_t)s[k] * 128 + sub * 4);
#pragma unroll
        for (int k = 0; k < 4; ++k) {
            ax += __uint_as_float((r[k].x & 0xffffu) << 16);
            ay += __uint_as_float(r[k].x & 0xffff0000u);
            az += __uint_as_float((r[k].y & 0xffffu) << 16);
            aw += __uint_as_float(r[k].y & 0xffff0000u);
        }
    }
    for (j += half; j < end; j += 2) {
        const int s = csr[j];
        const uint2 r = *reinterpret_cast<const uint2*>(h + (size_t)s * 128 + sub * 4);
        ax += __uint_as_float((r.x & 0xffffu) << 16);
        ay += __uint_as_float(r.x & 0xffff0000u);
        az += __uint_as_float((r.y & 0xffffu) << 16);
        aw += __uint_as_float(r.y & 0xffff0000u);
    }

    ax += __shfl_xor(ax, 32, 64);
    ay += __shfl_xor(ay, 32, 64);
    az += __shfl_xor(az, 32, 64);
    aw += __shfl_xor(aw, 32, 64);

    if (half == 0) {
        const float nm = rsqrtf(fmaxf((float)cnt, 1.0f));
        const float4 b = *reinterpret_cast<const float4*>(bias + sub * 4);
        float4 o;
        o.x = fmaf(ax, nm, b.x);
        o.y = fmaf(ay, nm, b.y);
        o.z = fmaf(az, nm, b.z);
        o.w = fmaf(aw, nm, b.w);
        *reinterpret_cast<float4*>(out + (size_t)node * 128 + sub * 4) = o;
    }
}

// ---------- Fallback path (ws too small for bf16 h) ----------
__global__ __launch_bounds__(256) void aggregate_f32(const float* __restrict__ feat,
                                                     const int* __restrict__ csr,
                                                     const int* __restrict__ off,
                                                     const int* __restrict__ deg,
                                                     float* __restrict__ out, int N) {
    const int node = (blockIdx.x * blockDim.x + threadIdx.x) >> 6;
    if (node >= N) return;
    const int lane = threadIdx.x & 63;
    const int start = off[node];
    const int end   = start + deg[node];
    const float2* feat2 = reinterpret_cast<const float2*>(feat);
    float ax = 0.0f, ay = 0.0f;
    for (int j = start; j < end; ++j) {
        const float2 v = feat2[(size_t)csr[j] * 64 + lane];
        ax += v.x;
        ay += v.y;
    }
    reinterpret_cast<float2*>(out)[(size_t)node * 64 + lane] = make_float2(ax, ay);
}

__global__ __launch_bounds__(256) void gemm_norm(const float* agg,
                                                 const float* __restrict__ weight,
                                                 const float* __restrict__ bias,
                                                 const int* __restrict__ deg,
                                                 float* out, int M) {
    __shared__ float As[64][68];
    __shared__ float Wc[64][128];
    const int t  = threadIdx.x;
    const int tx = t & 15;
    const int ty = t >> 4;
    const int row0 = blockIdx.x * 64;
    float acc[4][8];
#pragma unroll
    for (int i = 0; i < 4; ++i)
#pragma unroll
        for (int j = 0; j < 8; ++j) acc[i][j] = 0.0f;
    for (int c = 0; c < 2; ++c) {
        if (c) __syncthreads();
        {
            const int k4 = (t & 15) * 4;
            const int rbase = t >> 4;
#pragma unroll
            for (int p = 0; p < 4; ++p) {
                const int rr = rbase + p * 16;
                const int grow = row0 + rr;
                float4 v = make_float4(0.f, 0.f, 0.f, 0.f);
                if (grow < M)
                    v = *reinterpret_cast<const float4*>(&agg[(size_t)grow * 128 + c * 64 + k4]);
                *reinterpret_cast<float4*>(&As[rr][k4]) = v;
            }
        }
        {
#pragma unroll
            for (int p = 0; p < 8; ++p) {
                const int idx = (p * 256 + t) * 4;
                const int kk = idx >> 7;
                const int j = idx & 127;
                *reinterpret_cast<float4*>(&Wc[kk][j]) =
                    *reinterpret_cast<const float4*>(&weight[(c * 64 + kk) * 128 + j]);
            }
        }
        __syncthreads();
#pragma unroll 8
        for (int k = 0; k < 64; ++k) {
            float a[4];
#pragma unroll
            for (int i = 0; i < 4; ++i) a[i] = As[ty * 4 + i][k];
            const float4 b0 = *reinterpret_cast<const float4*>(&Wc[k][tx * 8 + 0]);
            const float4 b1 = *reinterpret_cast<const float4*>(&Wc[k][tx * 8 + 4]);
            const float b[8] = {b0.x, b0.y, b0.z, b0.w, b1.x, b1.y, b1.z, b1.w};
#pragma unroll
            for (int i = 0; i < 4; ++i)
#pragma unroll
                for (int j = 0; j < 8; ++j)
                    acc[i][j] = fmaf(a[i], b[j], acc[i][j]);
        }
    }
    float bcol[8];
#pragma unroll
    for (int j = 0; j < 8; ++j) bcol[j] = bias[tx * 8 + j];
#pragma unroll
    for (int i = 0; i < 4; ++i) {
        const int grow = row0 + ty * 4 + i;
        if (grow < M) {
            const float nm = rsqrtf(fmaxf((float)deg[grow], 1.0f));
            float4 o0, o1;
            o0.x = fmaf(acc[i][0], nm, bcol[0]);
            o0.y = fmaf(acc[i][1], nm, bcol[1]);
            o0.z = fmaf(acc[i][2], nm, bcol[2]);
            o0.w = fmaf(acc[i][3], nm, bcol[3]);
            o1.x = fmaf(acc[i][4], nm, bcol[4]);
            o1.y = fmaf(acc[i][5], nm, bcol[5]);
            o1.z = fmaf(acc[i][6], nm, bcol[6]);
            o1.w = fmaf(acc[i][7], nm, bcol[7]);
            *reinterpret_cast<float4*>(&out[(size_t)grow * 128 + tx * 8 + 0]) = o0;
            *reinterpret_cast<float4*>(&out[(size_t)grow * 128 + tx * 8 + 4]) = o1;
        }
    }
}

extern "C" void kernel_launch(void* const* d_in, const int* in_sizes, int n_in,
                              void* d_out, int out_size, void* d_ws, size_t ws_size,
                              hipStream_t stream) {
    const float* feat   = (const float*)d_in[0];
    const int*   src    = (const int*)d_in[1];
    const int*   dst    = (const int*)d_in[2];
    const float* weight = (const float*)d_in[3];
    const float* bias   = (const float*)d_in[4];
    float* out = (float*)d_out;

    const int nE = in_sizes[1];
    const int M  = in_sizes[0] / 128;
    const int P  = (M + CHUNK - 1) / CHUNK;

    // ws layout (ints): deg[M] | off[M] | cur[M] | partials[256] | csr[nE] | h(bf16, 16B-aligned)
    int* degi     = (int*)d_ws;
    int* off      = degi + M;
    int* cur      = off + M;
    int* partials = cur + M;
    int* csr      = partials + 256;
    const size_t csr_bytes = ((size_t)3 * M + 256 + (size_t)nE) * sizeof(int);
    const size_t h_off     = (csr_bytes + 15) & ~(size_t)15;
    ushort* h = (ushort*)((char*)d_ws + h_off);
    const size_t need_big = h_off + (size_t)M * 128 * sizeof(ushort);

    // CSR build (XCD-range partitioned hist + bucket, 2048 blocks for occupancy)
    hipMemsetAsync(degi, 0, (size_t)M * sizeof(int), stream);
    hist_part<<<8 * GROUPS, 256, 0, stream>>>(dst, degi, nE, M);
    scan_chunks<<<P, 256, 0, stream>>>(degi, off, partials, M);
    scan_partials<<<1, 64, 0, stream>>>(partials, P);
    add_base<<<(M + 255) / 256, 256, 0, stream>>>(off, cur, partials, M);
    bucket_part<<<8 * GROUPS, 256, 0, stream>>>(src, dst, cur, csr, nE, M);

    if (ws_size >= need_big) {
        gemm_h<<<(M + 63) / 64, 256, 0, stream>>>(feat, weight, h, M);
        aggregate_h<<<(M + 3) / 4, 256, 0, stream>>>(h, csr, off, degi, bias, out, M);
    } else {
        aggregate_f32<<<(M + 3) / 4, 256, 0, stream>>>(feat, csr, off, degi, out, M);
        gemm_norm<<<(M + 63) / 64, 256, 0, stream>>>(out, weight, bias, degi, out, M);
    }
}